// Round 3
// baseline (10762.935 us; speedup 1.0000x reference)
//
#include <hip/hip_runtime.h>
#include <math.h>

#define N 64
#define LDSP 65          // odd pitch: column access As[lane][p] conflict-free
#define SWEEPS 8
#define EPSV 1e-3
#define MAXEIG 1000.0

// One 64-thread wave per 64x64 symmetric matrix.
// Two-sided cyclic Jacobi, tournament ordering. A in LDS (padded pitch 65).
// V kept TRANSPOSED in LDS (Vt[k][j] = V[j][k], pitch 64): column rotations of
// V become stride-1 row ops on Vt, fused into A's column phase. No per-lane
// register arrays anywhere (round 1/2: compiler put v[64] in scratch -> 41 GB
// of HBM scratch writes = whole kernel time).
__global__ __launch_bounds__(64)
void spd_log_kernel(const float* __restrict__ x, float* __restrict__ out) {
    __shared__ float As[N][LDSP];   // A during Jacobi; V (natural) afterwards
    __shared__ float Vt[N][N];      // V^T; row k = eigenvector (column) k
    __shared__ float2 cs[N / 2];
    __shared__ float farr[N];

    const int lane = threadIdx.x;
    const size_t mat = blockIdx.x;
    const float* __restrict__ xm = x + mat * (size_t)(N * N);
    float* __restrict__ om = out + mat * (size_t)(N * N);

    for (int r = 0; r < N; ++r)
        As[r][lane] = xm[r * N + lane];
    for (int k = 0; k < N; ++k)
        Vt[k][lane] = (k == lane) ? 1.0f : 0.0f;
    __syncthreads();

    for (int sweep = 0; sweep < SWEEPS; ++sweep) {
        for (int r = 0; r < N - 1; ++r) {
            // --- rotation coefficients (lanes 0..31, pair k) ---
            if (lane < N / 2) {
                const int k = lane;
                const int p = (k == 0) ? 0 : 1 + (k - 1 + r) % 63;
                const int q = 1 + (62 - k + r) % 63;
                const float app = As[p][p];
                const float aqq = As[q][q];
                const float apq = As[p][q];
                float c = 1.0f, s = 0.0f;
                if (apq != 0.0f) {
                    const float tau = (aqq - app) / (2.0f * apq);
                    const float at = fabsf(tau);
                    float t = 1.0f / (at + sqrtf(1.0f + at * at));
                    t = copysignf(t, tau);
                    c = 1.0f / sqrtf(1.0f + t * t);
                    s = t * c;
                }
                cs[k] = make_float2(c, s);
            }
            __syncthreads();

            // --- row phase: rows p,q mix; lane = column ---
            {
                // i = 0: (p,q) = (0, 1+(62+r)%63)
                {
                    const int q = 1 + (62 + r) % 63;
                    const float2 t = cs[0];
                    const float rp = As[0][lane], rq = As[q][lane];
                    As[0][lane] = t.x * rp - t.y * rq;
                    As[q][lane] = t.y * rp + t.x * rq;
                }
                int p = 1 + r % 63;
                int q = 1 + (61 + r) % 63;
#pragma unroll 8
                for (int i = 1; i < N / 2; ++i) {
                    const float2 t = cs[i];
                    const float rp = As[p][lane], rq = As[q][lane];
                    As[p][lane] = t.x * rp - t.y * rq;
                    As[q][lane] = t.y * rp + t.x * rq;
                    p = (p == 63) ? 1 : p + 1;
                    q = (q == 1) ? 63 : q - 1;
                }
            }
            __syncthreads();

            // --- column phase: cols p,q of A (padded col access) and rows
            //     p,q of Vt (stride-1) share the same (c,s) ---
            {
                {
                    const int q = 1 + (62 + r) % 63;
                    const float2 t = cs[0];
                    const float cp = As[lane][0], cq = As[lane][q];
                    As[lane][0] = t.x * cp - t.y * cq;
                    As[lane][q] = t.y * cp + t.x * cq;
                    const float vp = Vt[0][lane], vq = Vt[q][lane];
                    Vt[0][lane] = t.x * vp - t.y * vq;
                    Vt[q][lane] = t.y * vp + t.x * vq;
                }
                int p = 1 + r % 63;
                int q = 1 + (61 + r) % 63;
#pragma unroll 8
                for (int i = 1; i < N / 2; ++i) {
                    const float2 t = cs[i];
                    const float cp = As[lane][p], cq = As[lane][q];
                    As[lane][p] = t.x * cp - t.y * cq;
                    As[lane][q] = t.y * cp + t.x * cq;
                    const float vp = Vt[p][lane], vq = Vt[q][lane];
                    Vt[p][lane] = t.x * vp - t.y * vq;
                    Vt[q][lane] = t.y * vp + t.x * vq;
                    p = (p == 63) ? 1 : p + 1;
                    q = (q == 1) ? 63 : q - 1;
                }
            }
            __syncthreads();
        }
    }

    // --- As <- V natural: As[lane][j] = V[lane][j] = Vt[j][lane] ---
    // write stride-65 (2 lanes/bank: free), read stride-1: conflict-free.
    for (int j = 0; j < N; ++j)
        As[lane][j] = Vt[j][lane];
    __syncthreads();

    // --- fp64 Rayleigh quotient vs ORIGINAL input: w = v^T X v / v^T v ---
    // v_c = As[c][lane] (padded column access, conflict-free). rr tiled by 8
    // so the vr values come from 8 regs instead of re-reads.
    {
        double nrm = 0.0, acc = 0.0;
        for (int rt = 0; rt < N / 8; ++rt) {
            float vr8[8];
#pragma unroll
            for (int t = 0; t < 8; ++t) vr8[t] = As[rt * 8 + t][lane];
#pragma unroll
            for (int t = 0; t < 8; ++t) nrm += (double)vr8[t] * (double)vr8[t];
            for (int c = 0; c < N; ++c) {
                const double vc = (double)As[c][lane];
                double inner = 0.0;
#pragma unroll
                for (int t = 0; t < 8; ++t)
                    inner += (double)xm[(rt * 8 + t) * N + c] * (double)vr8[t];
                acc += vc * inner;
            }
        }
        double wv = acc / nrm;
        wv = fmin(fmax(wv, (double)EPSV), (double)MAXEIG);
        farr[lane] = (float)log(wv);
    }
    __syncthreads();

    // --- scale Vt rows in place: Vt[j][lane] *= f_j ---
    for (int j = 0; j < N; ++j)
        Vt[j][lane] *= farr[j];
    __syncthreads();

    // --- reconstruct: Out[r][lane] = sum_j V[r][j] * (f_j * V[lane][j])
    //     = sum_j As[r][j] (broadcast) * Vt[j][lane] (stride-1, scaled) ---
    for (int rt = 0; rt < 4; ++rt) {
        float acc16[16];
#pragma unroll
        for (int t = 0; t < 16; ++t) acc16[t] = 0.0f;
        for (int j = 0; j < N; ++j) {
            const float gj = Vt[j][lane];
#pragma unroll
            for (int t = 0; t < 16; ++t)
                acc16[t] += As[rt * 16 + t][j] * gj;
        }
#pragma unroll
        for (int t = 0; t < 16; ++t)
            om[(rt * 16 + t) * N + lane] = acc16[t];
    }
}

extern "C" void kernel_launch(void* const* d_in, const int* in_sizes, int n_in,
                              void* d_out, int out_size, void* d_ws, size_t ws_size,
                              hipStream_t stream) {
    const float* x = (const float*)d_in[0];
    float* out = (float*)d_out;
    const int nmat = in_sizes[0] / (N * N);
    spd_log_kernel<<<dim3(nmat), dim3(64), 0, stream>>>(x, out);
}

// Round 4
// 6383.213 us; speedup vs baseline: 1.6861x; 1.6861x over previous
//
#include <hip/hip_runtime.h>
#include <math.h>

#define N 64
#define LDSP 65          // odd pitch: column access As[lane][p] is 2-way (free)
#define SWEEPS 7
#define EPSV 1e-3
#define MAXEIG 1000.0

// TWO 64-lane waves per 64x64 symmetric matrix (128 threads/block).
// Two-sided cyclic Jacobi, tournament ordering; the 32 rotation pairs of each
// round are split 16/16 across the waves in both phases (disjoint rows/cols).
// Round-3 build (1 wave/block) was latency-bound at 1 wave/SIMD (VALUBusy 23%,
// 13k cyc/round for ~800 instrs); same LDS with 2 waves/block -> 2 waves/SIMD.
// V kept transposed in LDS (Vt row k = eigenvector k): stride-1 row ops fused
// into A's column phase. No per-lane arrays with runtime indexing (scratch!).
__global__ __launch_bounds__(128, 2)
void spd_log_kernel(const float* __restrict__ x, float* __restrict__ out) {
    __shared__ float As[N][LDSP];   // A during Jacobi; V (natural) afterwards
    __shared__ float Vt[N][N];      // V^T
    __shared__ float2 cs[N / 2];
    __shared__ float farr[N];
    __shared__ double2 part[N];     // wave1 Rayleigh partials (acc, nrm)

    const int tid  = (int)threadIdx.x;
    const int lane = tid & 63;
    const int wid  = tid >> 6;
    const size_t mat = blockIdx.x;
    const float* __restrict__ xm = x + mat * (size_t)(N * N);
    float* __restrict__ om = out + mat * (size_t)(N * N);

    for (int r2 = wid; r2 < N; r2 += 2)
        As[r2][lane] = xm[r2 * N + lane];
    for (int k = wid; k < N; k += 2)
        Vt[k][lane] = (k == lane) ? 1.0f : 0.0f;
    __syncthreads();

    for (int sweep = 0; sweep < SWEEPS; ++sweep) {
        for (int r = 0; r < N - 1; ++r) {
            // --- rotation coefficients: lanes 0..31 of wave 0, pair k ---
            if (tid < N / 2) {
                const int k = tid;
                const int a = k - 1 + r;                      // <= 92
                const int p = (k == 0) ? 0 : 1 + (a >= 63 ? a - 63 : a);
                const int b = 62 - k + r;                     // <= 124
                const int q = 1 + (b >= 63 ? b - 63 : b);
                const float app = As[p][p];
                const float aqq = As[q][q];
                const float apq = As[p][q];
                float c = 1.0f, s = 0.0f;
                if (apq != 0.0f) {
                    const float tau = (aqq - app) / (2.0f * apq);
                    const float at = fabsf(tau);
                    float t = 1.0f / (at + sqrtf(1.0f + at * at));
                    t = copysignf(t, tau);
                    c = 1.0f / sqrtf(1.0f + t * t);
                    s = t * c;
                }
                cs[k] = make_float2(c, s);
            }
            __syncthreads();

            // --- row phase: wave wid handles pairs [wid*16, wid*16+16) ---
#pragma unroll
            for (int ii = 0; ii < 16; ++ii) {
                const int i = wid * 16 + ii;
                const int a = i - 1 + r;
                const int p = (i == 0) ? 0 : 1 + (a >= 63 ? a - 63 : a);
                const int b = 62 - i + r;
                const int q = 1 + (b >= 63 ? b - 63 : b);
                const float2 t = cs[i];
                const float rp = As[p][lane], rq = As[q][lane];
                As[p][lane] = t.x * rp - t.y * rq;
                As[q][lane] = t.y * rp + t.x * rq;
            }
            __syncthreads();

            // --- col phase (A cols p,q) + fused Vt row rotation ---
#pragma unroll
            for (int ii = 0; ii < 16; ++ii) {
                const int i = wid * 16 + ii;
                const int a = i - 1 + r;
                const int p = (i == 0) ? 0 : 1 + (a >= 63 ? a - 63 : a);
                const int b = 62 - i + r;
                const int q = 1 + (b >= 63 ? b - 63 : b);
                const float2 t = cs[i];
                const float cp = As[lane][p], cq = As[lane][q];
                As[lane][p] = t.x * cp - t.y * cq;
                As[lane][q] = t.y * cp + t.x * cq;
                const float vp = Vt[p][lane], vq = Vt[q][lane];
                Vt[p][lane] = t.x * vp - t.y * vq;
                Vt[q][lane] = t.y * vp + t.x * vq;
            }
            __syncthreads();
        }
    }

    // --- As <- V natural: As[i][j] = V[i][j] = Vt[j][i]; j split by wave ---
    for (int j = wid * 32; j < wid * 32 + 32; ++j)
        As[lane][j] = Vt[j][lane];
    __syncthreads();

    // --- fp64 Rayleigh vs ORIGINAL input, rows split across the two waves:
    //     w_lane = v^T X v / v^T v with v = column `lane` of V ---
    {
        double nrm = 0.0, acc = 0.0;
        for (int rt = wid * 4; rt < wid * 4 + 4; ++rt) {
            float vr8[8];
#pragma unroll
            for (int t = 0; t < 8; ++t) vr8[t] = As[rt * 8 + t][lane];
#pragma unroll
            for (int t = 0; t < 8; ++t) nrm += (double)vr8[t] * (double)vr8[t];
            for (int c = 0; c < N; ++c) {
                const double vc = (double)As[c][lane];
                double inner = 0.0;
#pragma unroll
                for (int t = 0; t < 8; ++t)
                    inner += (double)xm[(rt * 8 + t) * N + c] * (double)vr8[t];
                acc += vc * inner;
            }
        }
        if (wid == 1) part[lane] = make_double2(acc, nrm);
        __syncthreads();
        if (tid < N) {
            const double2 pw = part[lane];
            double wv = (acc + pw.x) / (nrm + pw.y);
            wv = fmin(fmax(wv, (double)EPSV), (double)MAXEIG);
            farr[lane] = (float)log(wv);
        }
    }
    __syncthreads();

    // --- scale Vt rows in place: Vt[j][lane] *= f_j; j split by wave ---
    for (int j = wid * 32; j < wid * 32 + 32; ++j)
        Vt[j][lane] *= farr[j];
    __syncthreads();

    // --- reconstruct Out[r][lane] = sum_j As[r][j] * Vt[j][lane];
    //     rows split by wave, 16-row register tiles ---
    for (int half = 0; half < 2; ++half) {
        const int r0 = wid * 32 + half * 16;
        float acc16[16];
#pragma unroll
        for (int t = 0; t < 16; ++t) acc16[t] = 0.0f;
        for (int j = 0; j < N; ++j) {
            const float gj = Vt[j][lane];
#pragma unroll
            for (int t = 0; t < 16; ++t)
                acc16[t] += As[r0 + t][j] * gj;
        }
#pragma unroll
        for (int t = 0; t < 16; ++t)
            om[(r0 + t) * N + lane] = acc16[t];
    }
}

extern "C" void kernel_launch(void* const* d_in, const int* in_sizes, int n_in,
                              void* d_out, int out_size, void* d_ws, size_t ws_size,
                              hipStream_t stream) {
    const float* x = (const float*)d_in[0];
    float* out = (float*)d_out;
    const int nmat = in_sizes[0] / (N * N);
    spd_log_kernel<<<dim3(nmat), dim3(128), 0, stream>>>(x, out);
}

// Round 5
// 4462.980 us; speedup vs baseline: 2.4116x; 1.4303x over previous
//
#include <hip/hip_runtime.h>
#include <math.h>

#define N 64
#define LDSP 65          // odd pitch: column access As[lane][p] is 2-way (free)
#define SWEEPS 7
#define EPSV 1e-3
#define MAXEIG 1000.0

// FOUR 64-lane waves per 64x64 symmetric matrix (256 threads/block).
// Two-sided cyclic Jacobi, tournament ordering; 32 pairs/round split 8 per
// wave. Key structural fixes vs round 4 (which ran at ~15 cyc/instr):
//  - read-all-then-write-all inside each phase: the compiler cannot prove
//    As[p_{i+1}][lane] doesn't alias the just-written As[q_i][lane], so the
//    fused loop serialized on ~120-cycle LDS round trips per pair.
//  - per-wave rotation coefficients (lanes 0..7) + v_readlane broadcast to
//    SGPRs; coeff reads touch only this wave's rows -> no coeff barrier.
//    2 barriers/round instead of 3, and c,s become scalar FMA operands.
//  - pair indices derived from readfirstlane(wid) -> SALU, no VGPR math.
__global__ __launch_bounds__(256, 4)
void spd_log_kernel(const float* __restrict__ x, float* __restrict__ out) {
    __shared__ float As[N][LDSP];   // A during Jacobi; V (natural) afterwards
    __shared__ float Vt[N][N];      // V^T; row k = eigenvector k
    __shared__ float farr[N];
    __shared__ double2 part[3][N];  // Rayleigh partials of waves 1..3

    const int tid  = (int)threadIdx.x;
    const int lane = tid & 63;
    const int wid  = __builtin_amdgcn_readfirstlane(tid >> 6);
    const size_t mat = blockIdx.x;
    const float* __restrict__ xm = x + mat * (size_t)(N * N);
    float* __restrict__ om = out + mat * (size_t)(N * N);

#pragma unroll
    for (int t = 0; t < 16; ++t) {
        const int r2 = wid * 16 + t;
        As[r2][lane] = xm[r2 * N + lane];
        Vt[r2][lane] = (r2 == lane) ? 1.0f : 0.0f;
    }
    __syncthreads();

    for (int sweep = 0; sweep < SWEEPS; ++sweep) {
        for (int r = 0; r < N - 1; ++r) {
            // ---- coefficients for this wave's 8 pairs (lanes 0..7) ----
            float cv = 1.0f, sv = 0.0f;
            if (lane < 8) {
                const int i = wid * 8 + lane;
                int a = i - 1 + r; if (a >= 63) a -= 63;
                const int p = (i == 0) ? 0 : 1 + a;
                int b = 62 - i + r; if (b >= 63) b -= 63;
                const int q = 1 + b;
                const float app = As[p][p];
                const float aqq = As[q][q];
                const float apq = As[p][q];
                if (apq != 0.0f) {
                    const float tau = (aqq - app) / (2.0f * apq);
                    const float at = fabsf(tau);
                    float t2 = 1.0f / (at + sqrtf(1.0f + at * at));
                    t2 = copysignf(t2, tau);
                    cv = 1.0f / sqrtf(1.0f + t2 * t2);
                    sv = t2 * cv;
                }
            }
            // broadcast (c,s) of pair wid*8+j to scalar regs
            float cj[8], sj[8];
#pragma unroll
            for (int j = 0; j < 8; ++j) {
                cj[j] = __uint_as_float(__builtin_amdgcn_readlane(__float_as_uint(cv), j));
                sj[j] = __uint_as_float(__builtin_amdgcn_readlane(__float_as_uint(sv), j));
            }
            // scalar pair indices (uniform: wid is readfirstlane'd)
            int pp[8], qq[8];
#pragma unroll
            for (int ii = 0; ii < 8; ++ii) {
                const int i = wid * 8 + ii;
                int a = i - 1 + r; if (a >= 63) a -= 63;
                pp[ii] = (i == 0) ? 0 : 1 + a;
                int b = 62 - i + r; if (b >= 63) b -= 63;
                qq[ii] = 1 + b;
            }

            // ---- row phase: gather all, then scatter all ----
            float rp[8], rq[8];
#pragma unroll
            for (int ii = 0; ii < 8; ++ii) {
                rp[ii] = As[pp[ii]][lane];
                rq[ii] = As[qq[ii]][lane];
            }
#pragma unroll
            for (int ii = 0; ii < 8; ++ii) {
                As[pp[ii]][lane] = cj[ii] * rp[ii] - sj[ii] * rq[ii];
                As[qq[ii]][lane] = sj[ii] * rp[ii] + cj[ii] * rq[ii];
            }
            __syncthreads();

            // ---- col phase (A cols) + fused Vt row rotation ----
            float cp[8], cq[8], vp[8], vq[8];
#pragma unroll
            for (int ii = 0; ii < 8; ++ii) {
                cp[ii] = As[lane][pp[ii]];
                cq[ii] = As[lane][qq[ii]];
                vp[ii] = Vt[pp[ii]][lane];
                vq[ii] = Vt[qq[ii]][lane];
            }
#pragma unroll
            for (int ii = 0; ii < 8; ++ii) {
                As[lane][pp[ii]] = cj[ii] * cp[ii] - sj[ii] * cq[ii];
                As[lane][qq[ii]] = sj[ii] * cp[ii] + cj[ii] * cq[ii];
                Vt[pp[ii]][lane] = cj[ii] * vp[ii] - sj[ii] * vq[ii];
                Vt[qq[ii]][lane] = sj[ii] * vp[ii] + cj[ii] * vq[ii];
            }
            __syncthreads();
        }
    }

    // ---- As <- V natural: As[i][j] = Vt[j][i]; j split by wave ----
#pragma unroll
    for (int t = 0; t < 16; ++t) {
        const int j = wid * 16 + t;
        As[lane][j] = Vt[j][lane];
    }
    __syncthreads();

    // ---- fp64 Rayleigh vs ORIGINAL input; 16 rows per wave ----
    {
        double nrm = 0.0, acc = 0.0;
#pragma unroll
        for (int rt = 0; rt < 2; ++rt) {
            const int r0 = wid * 16 + rt * 8;
            float vr8[8];
#pragma unroll
            for (int t = 0; t < 8; ++t) vr8[t] = As[r0 + t][lane];
#pragma unroll
            for (int t = 0; t < 8; ++t) nrm += (double)vr8[t] * (double)vr8[t];
            for (int c = 0; c < N; ++c) {
                const double vc = (double)As[c][lane];
                double inner = 0.0;
#pragma unroll
                for (int t = 0; t < 8; ++t)
                    inner += (double)xm[(r0 + t) * N + c] * (double)vr8[t];
                acc += vc * inner;
            }
        }
        if (wid > 0) part[wid - 1][lane] = make_double2(acc, nrm);
        __syncthreads();
        if (wid == 0) {
#pragma unroll
            for (int k = 0; k < 3; ++k) {
                acc += part[k][lane].x;
                nrm += part[k][lane].y;
            }
            double wv = acc / nrm;
            wv = fmin(fmax(wv, (double)EPSV), (double)MAXEIG);
            farr[lane] = (float)log(wv);
        }
    }
    __syncthreads();

    // ---- scale Vt rows in place: Vt[j][lane] *= f_j; j split by wave ----
#pragma unroll
    for (int t = 0; t < 16; ++t) {
        const int j = wid * 16 + t;
        Vt[j][lane] *= farr[j];
    }
    __syncthreads();

    // ---- reconstruct Out[r][lane] = sum_j As[r][j] * Vt[j][lane];
    //      16 rows per wave, register accumulators ----
    {
        const int r0 = wid * 16;
        float acc16[16];
#pragma unroll
        for (int t = 0; t < 16; ++t) acc16[t] = 0.0f;
        for (int j = 0; j < N; ++j) {
            const float gj = Vt[j][lane];
#pragma unroll
            for (int t = 0; t < 16; ++t)
                acc16[t] += As[r0 + t][j] * gj;
        }
#pragma unroll
        for (int t = 0; t < 16; ++t)
            om[(r0 + t) * N + lane] = acc16[t];
    }
}

extern "C" void kernel_launch(void* const* d_in, const int* in_sizes, int n_in,
                              void* d_out, int out_size, void* d_ws, size_t ws_size,
                              hipStream_t stream) {
    const float* x = (const float*)d_in[0];
    float* out = (float*)d_out;
    const int nmat = in_sizes[0] / (N * N);
    spd_log_kernel<<<dim3(nmat), dim3(256), 0, stream>>>(x, out);
}